// Round 1
// baseline (1213.208 us; speedup 1.0000x reference)
//
#include <hip/hip_runtime.h>
#include <utility>
#include <cstddef>

#define SUBN 20
#define EN   2000
#define TN   50
#define HIDN 10
#define CHN  200     // SUBN*HIDN
#define BN   8
#define TD   5000
#define TP   5056    // 79*64 padded T
#define NOB  79

// workspace layout (float offsets)
#define OFF_CP  0                      // 20*2000 = 40000
#define OFF_G   40000                  // 200
#define OFF_SYN 40200                  // 8*20*5056 = 808960
#define OFF_U   849160                 // 8*200*5056 = 8089600
#define OFF_Y   8938760                // 8*200*5056 = 8089600
// total 17,028,360 floats = 68.1 MB

// ---------------- prep: C' = C_syn_e * exp(E_scale), g = exp(W_layer2) ----
__global__ __launch_bounds__(256) void k_prep(const float* __restrict__ Ce,
                                              const float* __restrict__ Es,
                                              const float* __restrict__ W2,
                                              float* __restrict__ Cp,
                                              float* __restrict__ g) {
    int idx = blockIdx.x * 256 + threadIdx.x;
    if (idx < SUBN * EN) {
        int e = idx % EN;
        Cp[idx] = Ce[idx] * __expf(Es[e]);
    } else if (idx < SUBN * EN + CHN) {
        g[idx - SUBN * EN] = __expf(W2[idx - SUBN * EN]);
    }
}

// ---------------- phase A: syn[b][s][t] = sum_e Se[b][t][e]*Cp[s][e] -------
__global__ __launch_bounds__(256) void k_gemm(const float* __restrict__ Se,
                                              const float* __restrict__ Cp,
                                              float* __restrict__ syn) {
    __shared__ float Sl[64 * 202];   // 64 t rows, 200 e cols, stride 202 (2-way LDS ok)
    const int b    = blockIdx.x / NOB;
    const int tile = blockIdx.x % NOB;
    const int t0   = tile * 64;
    const int tid  = threadIdx.x;
    const int tr   = tid & 63;       // t within tile (lane id -> wave-uniform C addrs)
    const int sg   = tid >> 6;       // wave id = s-group
    float acc[5] = {0.f, 0.f, 0.f, 0.f, 0.f};
    for (int ch = 0; ch < 10; ++ch) {
        const int e0 = ch * 200;
        __syncthreads();
        // stage 64x200 floats as 6400 float2 (coalesced)
        for (int k = 0; k < 25; ++k) {
            int idx = tid + k * 256;
            int r   = idx / 100;
            int c2  = idx - r * 100;
            int t   = t0 + r;
            float2 v = make_float2(0.f, 0.f);
            if (t < TD) v = *(const float2*)(Se + (size_t)(b * TD + t) * EN + e0 + 2 * c2);
            *(float2*)(&Sl[r * 202 + 2 * c2]) = v;
        }
        __syncthreads();
        const float* crow = Cp + (sg * 5) * EN + e0;
        for (int e = 0; e < 200; e += 4) {
            float4 cv[5];
            #pragma unroll
            for (int j = 0; j < 5; ++j) cv[j] = *(const float4*)(crow + j * EN + e);
            float2 sa = *(const float2*)(&Sl[tr * 202 + e]);
            float2 sb = *(const float2*)(&Sl[tr * 202 + e + 2]);
            #pragma unroll
            for (int j = 0; j < 5; ++j) {
                acc[j] = fmaf(sa.x, cv[j].x, acc[j]);
                acc[j] = fmaf(sa.y, cv[j].y, acc[j]);
                acc[j] = fmaf(sb.x, cv[j].z, acc[j]);
                acc[j] = fmaf(sb.y, cv[j].w, acc[j]);
            }
        }
    }
    float* so = syn + (size_t)(b * SUBN + sg * 5) * TP + t0 + tr;
    #pragma unroll
    for (int j = 0; j < 5; ++j) so[(size_t)j * TP] = acc[j];
}

// ---------------- phase B: u[b][c][t] = b1[c] + sum_j W1[c][j]*syn[b][s][t-j]
__global__ __launch_bounds__(256) void k_conv(const float* __restrict__ syn,
                                              const float* __restrict__ W1,
                                              const float* __restrict__ b1,
                                              float* __restrict__ u) {
    __shared__ float srow[52 + TP];  // 52 leading zeros kill boundary guards
    __shared__ float Wl[500];
    __shared__ float bl[HIDN];
    const int b = blockIdx.x / SUBN;
    const int s = blockIdx.x % SUBN;
    const int tid = threadIdx.x;
    for (int i = tid; i < 52; i += 256) srow[i] = 0.f;
    for (int i = tid; i < TP; i += 256)
        srow[52 + i] = syn[(size_t)(b * SUBN + s) * TP + i];
    for (int i = tid; i < 500; i += 256) Wl[i] = W1[s * 500 + i];  // rows c=s*10..s*10+9 contiguous
    if (tid < HIDN) bl[tid] = b1[s * HIDN + tid];
    __syncthreads();
    // 10 h * (TP/4)=1264 four-t chunks = 12640 tasks
    for (int k = 0; k < 50; ++k) {
        int task = tid + k * 256;
        if (task >= 10 * (TP / 4)) break;
        int h  = task / (TP / 4);
        int tc = task - h * (TP / 4);
        int t0 = tc * 4;
        float a0, a1, a2, a3;
        a0 = a1 = a2 = a3 = bl[h];
        const float* wp = &Wl[h * 50];
        const float* sp = &srow[52 + t0];
        #pragma unroll
        for (int j = 0; j < 50; ++j) {
            float w = wp[j];
            a0 = fmaf(w, sp[0 - j], a0);
            a1 = fmaf(w, sp[1 - j], a1);
            a2 = fmaf(w, sp[2 - j], a2);
            a3 = fmaf(w, sp[3 - j], a3);
        }
        float4 o = make_float4(a0, a1, a2, a3);
        *(float4*)(u + (size_t)(b * CHN + s * HIDN + h) * TP + t0) = o;
    }
}

// ---------------- phase C: the recurrence ---------------------------------
// 16 lanes per (b,c) channel. 64-slot transposed-FIR ring of future partial
// sums, 4 slots/lane (slot j owned by lane j&15). Near taps d=1..6 replicated
// in all lanes (pend ring of 8, indexed t&7); far taps d=7..50 distributed.
// Far value for step t+6 broadcast via ds_swizzle 2 steps early.
struct Rec {
    float wl[64];          // rotated far-weight ring: wl[m] = wfar[(lane16+m)&63]
    float wn1, wn2, wn3, wn4, wn5, wn6;
    float acc0, acc1, acc2, acc3;
    float pend[8];
    float yv[8];
    float4 upipe[8];
    float4 cur;
    float bval;
    const float* urow;
    float* yrow8;
    int lane16;
    int tbase;
    bool m0, m1, m2, storer;
};

template<int P>
__device__ __forceinline__ void rec_step(Rec& S) {
    // u prefetch pipeline: consume one float4 per 4 phases, refill 32 ahead
    if constexpr ((P & 3) == 0) {
        constexpr int Q = (P >> 2) & 7;
        S.cur = S.upipe[Q];
        int tl = S.tbase + P + 32;
        if (tl > TP - 4) tl = TP - 4;
        S.upipe[Q] = *(const float4*)(&S.urow[tl]);
    }
    float uval;
    if constexpr ((P & 3) == 0) uval = S.cur.x;
    else if constexpr ((P & 3) == 1) uval = S.cur.y;
    else if constexpr ((P & 3) == 2) uval = S.cur.z;
    else uval = S.cur.w;

    float pre = S.pend[P & 7] + uval;
    // tanh(x) = 1 - 2/(exp2(x*2*log2e)+1)
    float ex = __builtin_amdgcn_exp2f(pre * 2.8853900817779268f);
    float rc = __builtin_amdgcn_rcpf(ex + 1.0f);
    float y  = __builtin_fmaf(-2.0f, rc, 1.0f);
    S.yv[P & 7] = y;

    // far updates: slot j = lane16 + 16k gets w_ring[(j - P)&63] = wl[(16k-P)&63]
    S.acc0 = __builtin_fmaf(S.wl[( 64 - P) & 63], y, S.acc0);
    S.acc1 = __builtin_fmaf(S.wl[( 80 - P) & 63], y, S.acc1);
    S.acc2 = __builtin_fmaf(S.wl[( 96 - P) & 63], y, S.acc2);
    S.acc3 = __builtin_fmaf(S.wl[(112 - P) & 63], y, S.acc3);

    // near updates: create pend for t+6 from bval (far part, swizzled at P-1),
    // and add taps d=1..5 into upcoming pends
    S.pend[(P + 6) & 7] = __builtin_fmaf(S.wn6, y, S.bval);
    S.pend[(P + 1) & 7] = __builtin_fmaf(S.wn1, y, S.pend[(P + 1) & 7]);
    S.pend[(P + 2) & 7] = __builtin_fmaf(S.wn2, y, S.pend[(P + 2) & 7]);
    S.pend[(P + 3) & 7] = __builtin_fmaf(S.wn3, y, S.pend[(P + 3) & 7]);
    S.pend[(P + 4) & 7] = __builtin_fmaf(S.wn4, y, S.pend[(P + 4) & 7]);
    S.pend[(P + 5) & 7] = __builtin_fmaf(S.wn5, y, S.pend[(P + 5) & 7]);

    // broadcast far acc of slot (P+7) (complete: last far tap d=7 added above)
    // and reset it on its owner lane for the next go-round
    constexpr int SB  = (P + 7) & 63;
    constexpr int KB  = SB >> 4;
    constexpr int OWB = SB & 15;
    float av;
    if constexpr (KB == 0) av = S.acc0;
    else if constexpr (KB == 1) av = S.acc1;
    else if constexpr (KB == 2) av = S.acc2;
    else av = S.acc3;
    S.bval = __int_as_float(
        __builtin_amdgcn_ds_swizzle(__float_as_int(av), (OWB << 5) | 0x10));
    float nv = (S.lane16 == OWB) ? 0.0f : av;
    if constexpr (KB == 0) S.acc0 = nv;
    else if constexpr (KB == 1) S.acc1 = nv;
    else if constexpr (KB == 2) S.acc2 = nv;
    else S.acc3 = nv;

    // batched coalesced store every 8 phases (lanes 0..7 of the group)
    if constexpr ((P & 7) == 7) {
        float a0 = S.m0 ? S.yv[1] : S.yv[0];
        float a1 = S.m0 ? S.yv[3] : S.yv[2];
        float a2 = S.m0 ? S.yv[5] : S.yv[4];
        float a3 = S.m0 ? S.yv[7] : S.yv[6];
        float b0 = S.m1 ? a1 : a0;
        float b1 = S.m1 ? a3 : a2;
        float sv = S.m2 ? b1 : b0;
        if (S.storer) S.yrow8[S.tbase + P - 7] = sv;
    }
}

template<int... Ps>
__device__ __forceinline__ void rec_steps(Rec& S, std::integer_sequence<int, Ps...>) {
    (rec_step<Ps>(S), ...);
}

__global__ __launch_bounds__(256) void k_rec(const float* __restrict__ u,
                                             const float* __restrict__ Wh,
                                             float* __restrict__ ybuf) {
    const int tid   = blockIdx.x * 256 + threadIdx.x;
    const int group = tid >> 4;          // 0..1599 == b*200 + c
    Rec S;
    S.lane16 = tid & 15;
    const int c = group % CHN;
    S.urow  = u    + (size_t)group * TP;
    S.yrow8 = ybuf + (size_t)group * TP + (S.lane16 & 7);
    S.m0 = (S.lane16 & 1) != 0;
    S.m1 = (S.lane16 & 2) != 0;
    S.m2 = (S.lane16 & 4) != 0;
    S.storer = S.lane16 < 8;
    const float* whc = Wh + c * TN;
    S.wn1 = whc[0]; S.wn2 = whc[1]; S.wn3 = whc[2];
    S.wn4 = whc[3]; S.wn5 = whc[4]; S.wn6 = whc[5];
    #pragma unroll
    for (int m = 0; m < 64; ++m) {
        int d = (S.lane16 + m) & 63;
        S.wl[m] = (d >= 7 && d <= TN) ? whc[d - 1] : 0.0f;
    }
    S.acc0 = S.acc1 = S.acc2 = S.acc3 = 0.f;
    #pragma unroll
    for (int i = 0; i < 8; ++i) S.pend[i] = 0.f;
    S.bval = 0.f;
    #pragma unroll
    for (int q = 0; q < 8; ++q) S.upipe[q] = *(const float4*)(&S.urow[4 * q]);

    for (int ob = 0; ob < NOB; ++ob) {
        S.tbase = ob * 64;
        rec_steps(S, std::make_integer_sequence<int, 64>{});
    }
}

// ---------------- phase D: out[b][t] = Vo + sum_c g[c]*y[b][c][t] ----------
__global__ __launch_bounds__(256) void k_out(const float* __restrict__ ybuf,
                                             const float* __restrict__ g,
                                             const float* __restrict__ Vo,
                                             float* __restrict__ out) {
    __shared__ float gl[CHN];
    const int tid = threadIdx.x;
    if (tid < CHN) gl[tid] = g[tid];
    __syncthreads();
    const int idx = blockIdx.x * 256 + tid;
    if (idx >= BN * TD) return;
    const int b = idx / TD;
    const int t = idx - b * TD;
    const float* yp = ybuf + (size_t)b * CHN * TP + t;
    float acc = Vo[0];
    #pragma unroll 8
    for (int cc = 0; cc < CHN; ++cc) acc = fmaf(gl[cc], yp[(size_t)cc * TP], acc);
    out[idx] = acc;
}

// ---------------------------------------------------------------------------
extern "C" void kernel_launch(void* const* d_in, const int* in_sizes, int n_in,
                              void* d_out, int out_size, void* d_ws, size_t ws_size,
                              hipStream_t stream) {
    const float* Se = (const float*)d_in[0];
    const float* Ce = (const float*)d_in[2];
    const float* Es = (const float*)d_in[4];
    const float* W1 = (const float*)d_in[6];
    const float* W2 = (const float*)d_in[7];
    const float* b1 = (const float*)d_in[8];
    const float* Wh = (const float*)d_in[9];
    const float* Vo = (const float*)d_in[11];
    float* ws  = (float*)d_ws;
    float* Cp  = ws + OFF_CP;
    float* g   = ws + OFF_G;
    float* syn = ws + OFF_SYN;
    float* u   = ws + OFF_U;
    float* yb  = ws + OFF_Y;
    float* out = (float*)d_out;

    hipLaunchKernelGGL(k_prep, dim3(158), dim3(256), 0, stream, Ce, Es, W2, Cp, g);
    hipLaunchKernelGGL(k_gemm, dim3(BN * NOB), dim3(256), 0, stream, Se, Cp, syn);
    hipLaunchKernelGGL(k_conv, dim3(BN * SUBN), dim3(256), 0, stream, syn, W1, b1, u);
    hipLaunchKernelGGL(k_rec,  dim3(100), dim3(256), 0, stream, u, Wh, yb);
    hipLaunchKernelGGL(k_out,  dim3((BN * TD + 255) / 256), dim3(256), 0, stream, yb, g, Vo, out);
}

// Round 2
// 880.084 us; speedup vs baseline: 1.3785x; 1.3785x over previous
//
#include <hip/hip_runtime.h>
#include <utility>
#include <cstddef>

#define SUBN 20
#define EN   2000
#define TN   50
#define HIDN 10
#define CHN  200     // SUBN*HIDN
#define BN   8
#define TD   5000
#define TP   5056    // 79*64 padded T
#define NOB  79

// workspace layout (float offsets)
#define OFF_CP  0                      // 20*2000 = 40000
#define OFF_G   40000                  // 200
#define OFF_SYN 40200                  // 8*20*5056 = 808960
#define OFF_U   849160                 // 8*200*5056 = 8089600
#define OFF_Y   8938760                // 8*200*5056 = 8089600
// total 17,028,360 floats = 68.1 MB

// ---------------- prep: C' = C_syn_e * exp(E_scale), g = exp(W_layer2) ----
__global__ __launch_bounds__(256) void k_prep(const float* __restrict__ Ce,
                                              const float* __restrict__ Es,
                                              const float* __restrict__ W2,
                                              float* __restrict__ Cp,
                                              float* __restrict__ g) {
    int idx = blockIdx.x * 256 + threadIdx.x;
    if (idx < SUBN * EN) {
        int e = idx % EN;
        Cp[idx] = Ce[idx] * __expf(Es[e]);
    } else if (idx < SUBN * EN + CHN) {
        g[idx - SUBN * EN] = __expf(W2[idx - SUBN * EN]);
    }
}

// ---------------- wave-wide sum via DPP (VALU pipe), result in lane 63 ----
__device__ __forceinline__ float wred(float x) {
    x += __int_as_float(__builtin_amdgcn_update_dpp(0, __float_as_int(x), 0x111, 0xF, 0xF, true)); // row_shr:1
    x += __int_as_float(__builtin_amdgcn_update_dpp(0, __float_as_int(x), 0x112, 0xF, 0xF, true)); // row_shr:2
    x += __int_as_float(__builtin_amdgcn_update_dpp(0, __float_as_int(x), 0x114, 0xF, 0xF, true)); // row_shr:4
    x += __int_as_float(__builtin_amdgcn_update_dpp(0, __float_as_int(x), 0x118, 0xF, 0xF, true)); // row_shr:8
    x += __int_as_float(__builtin_amdgcn_update_dpp(0, __float_as_int(x), 0x142, 0xF, 0xF, true)); // row_bcast:15
    x += __int_as_float(__builtin_amdgcn_update_dpp(0, __float_as_int(x), 0x143, 0xF, 0xF, true)); // row_bcast:31
    return x;
}

// ---------------- phase A: syn[b][s][t] = sum_e Se[b][t][e]*Cp[s][e] -------
// Lanes over e (lane owns e = 4*lane + 256k), 8 t-rows per wave. No LDS, no
// barriers. Se coalesced float4 from HBM, Cp coalesced float4 from L2
// (160 KB, resident). 20x8 partial accs per lane, DPP-reduced at the end.
__global__ __launch_bounds__(256, 2) void k_gemm(const float* __restrict__ Se,
                                                 const float* __restrict__ Cp,
                                                 float* __restrict__ syn) {
    const int tid  = threadIdx.x;
    const int lane = tid & 63;
    const int wave = tid >> 6;
    const int r0   = blockIdx.x * 32 + wave * 8;   // first of 8 rows (b*TD+t)
    const size_t rbase = (size_t)r0 * EN;
    const int le   = 4 * lane;
    const bool ok7 = (le < 208);                   // k=7 chunk covers e 1792..1999

    float acc[SUBN][8];
    #pragma unroll
    for (int s = 0; s < SUBN; ++s)
        #pragma unroll
        for (int t = 0; t < 8; ++t) acc[s][t] = 0.0f;

    for (int k = 0; k < 8; ++k) {
        int coff = 256 * k + le;
        if (k == 7 && !ok7) coff = 0;              // clamp OOB lanes to safe addr
        float4 se[8];
        #pragma unroll
        for (int t = 0; t < 8; ++t)
            se[t] = *(const float4*)(Se + rbase + (size_t)t * EN + coff);
        if (k == 7 && !ok7) {
            #pragma unroll
            for (int t = 0; t < 8; ++t) se[t] = make_float4(0.f, 0.f, 0.f, 0.f);
        }
        const float* cp0 = Cp + 256 * k + le;      // OOB tail reads hit g[] region: finite, *0
        #pragma unroll
        for (int s = 0; s < SUBN; ++s) {
            float4 cv = *(const float4*)(cp0 + s * EN);
            #pragma unroll
            for (int t = 0; t < 8; ++t) {
                acc[s][t] = fmaf(cv.x, se[t].x, acc[s][t]);
                acc[s][t] = fmaf(cv.y, se[t].y, acc[s][t]);
                acc[s][t] = fmaf(cv.z, se[t].z, acc[s][t]);
                acc[s][t] = fmaf(cv.w, se[t].w, acc[s][t]);
            }
        }
    }

    #pragma unroll
    for (int s = 0; s < SUBN; ++s)
        #pragma unroll
        for (int t = 0; t < 8; ++t) acc[s][t] = wred(acc[s][t]);

    if (lane == 63) {
        #pragma unroll
        for (int t = 0; t < 8; ++t) {
            int r  = r0 + t;
            int b  = r / TD;
            int tt = r - b * TD;
            float* sp = syn + (size_t)(b * SUBN) * TP + tt;
            #pragma unroll
            for (int s = 0; s < SUBN; ++s) sp[(size_t)s * TP] = acc[s][t];
        }
    }
}

// ---------------- phase B: u[b][c][t] = b1[c] + sum_j W1[c][j]*syn[b][s][t-j]
// One block per (b,s,h): 1600 blocks. FIR weights in 50 VGPRs; 7 outputs per
// thread (lane stride 7 words -> conflict-free LDS); 56 x-reads per 350 FMA.
__global__ __launch_bounds__(256, 4) void k_conv(const float* __restrict__ syn,
                                                 const float* __restrict__ W1,
                                                 const float* __restrict__ b1,
                                                 float* __restrict__ u) {
    __shared__ __align__(16) float srow[52 + TP + 12];   // 5120 floats
    const int bs  = blockIdx.x / HIDN;   // b*20+s
    const int h   = blockIdx.x % HIDN;
    const int s   = bs % SUBN;
    const int tid = threadIdx.x;

    // stage: zeros head [0,52), syn row, zeros tail
    for (int i = tid; i < 13; i += 256) ((float4*)srow)[i] = make_float4(0,0,0,0);
    for (int i = tid; i < 3; i += 256)
        ((float4*)(srow + 52 + TP))[i] = make_float4(0,0,0,0);
    const float4* srcp = (const float4*)(syn + (size_t)bs * TP);
    for (int i = tid; i < TP / 4; i += 256) ((float4*)(srow + 52))[i] = srcp[i];

    const int c = s * HIDN + h;
    float wreg[TN];
    #pragma unroll
    for (int j = 0; j < TN; ++j) wreg[j] = W1[c * TN + j];   // broadcast, L2
    const float bh = b1[c];
    __syncthreads();

    float* urow = u + (size_t)(bs * HIDN + h) * TP;
    for (int task = 0; task < 3; ++task) {
        int gidx = tid + task * 256;
        if (gidx >= 723) break;                  // 723 groups of 7 cover 5056+
        int t0 = gidx * 7;
        float a[7];
        #pragma unroll
        for (int m = 0; m < 7; ++m) a[m] = bh;
        #pragma unroll
        for (int kk = 0; kk < 56; ++kk) {
            int k = kk - 49;                     // x index offset, j = m - k
            float xv = srow[52 + t0 + k];
            #pragma unroll
            for (int m = 0; m < 7; ++m) {
                int j = m - k;
                if (j >= 0 && j < TN) a[m] = fmaf(wreg[j], xv, a[m]);
            }
        }
        #pragma unroll
        for (int m = 0; m < 7; ++m) {
            int t = t0 + m;
            if (t < TP) urow[t] = a[m];
        }
    }
}

// ---------------- phase C: the recurrence ---------------------------------
// 16 lanes per (b,c) channel. 64-slot transposed-FIR ring of future partial
// sums, 4 slots/lane (slot j owned by lane j&15). Near taps d=1..6 replicated
// in all lanes (pend ring of 8, indexed t&7); far taps d=7..50 distributed.
// Far value for step t+6 broadcast via ds_swizzle 2 steps early.
struct Rec {
    float wl[64];          // rotated far-weight ring: wl[m] = wfar[(lane16+m)&63]
    float wn1, wn2, wn3, wn4, wn5, wn6;
    float acc0, acc1, acc2, acc3;
    float pend[8];
    float yv[8];
    float4 upipe[8];
    float4 cur;
    float bval;
    const float* urow;
    float* yrow8;
    int lane16;
    int tbase;
    bool m0, m1, m2, storer;
};

template<int P>
__device__ __forceinline__ void rec_step(Rec& S) {
    // u prefetch pipeline: consume one float4 per 4 phases, refill 32 ahead
    if constexpr ((P & 3) == 0) {
        constexpr int Q = (P >> 2) & 7;
        S.cur = S.upipe[Q];
        int tl = S.tbase + P + 32;
        if (tl > TP - 4) tl = TP - 4;
        S.upipe[Q] = *(const float4*)(&S.urow[tl]);
    }
    float uval;
    if constexpr ((P & 3) == 0) uval = S.cur.x;
    else if constexpr ((P & 3) == 1) uval = S.cur.y;
    else if constexpr ((P & 3) == 2) uval = S.cur.z;
    else uval = S.cur.w;

    float pre = S.pend[P & 7] + uval;
    // tanh(x) = 1 - 2/(exp2(x*2*log2e)+1)
    float ex = __builtin_amdgcn_exp2f(pre * 2.8853900817779268f);
    float rc = __builtin_amdgcn_rcpf(ex + 1.0f);
    float y  = __builtin_fmaf(-2.0f, rc, 1.0f);
    S.yv[P & 7] = y;

    // far updates: slot j = lane16 + 16k gets w_ring[(j - P)&63] = wl[(16k-P)&63]
    S.acc0 = __builtin_fmaf(S.wl[( 64 - P) & 63], y, S.acc0);
    S.acc1 = __builtin_fmaf(S.wl[( 80 - P) & 63], y, S.acc1);
    S.acc2 = __builtin_fmaf(S.wl[( 96 - P) & 63], y, S.acc2);
    S.acc3 = __builtin_fmaf(S.wl[(112 - P) & 63], y, S.acc3);

    // near updates: create pend for t+6 from bval (far part, swizzled at P-1),
    // and add taps d=1..5 into upcoming pends
    S.pend[(P + 6) & 7] = __builtin_fmaf(S.wn6, y, S.bval);
    S.pend[(P + 1) & 7] = __builtin_fmaf(S.wn1, y, S.pend[(P + 1) & 7]);
    S.pend[(P + 2) & 7] = __builtin_fmaf(S.wn2, y, S.pend[(P + 2) & 7]);
    S.pend[(P + 3) & 7] = __builtin_fmaf(S.wn3, y, S.pend[(P + 3) & 7]);
    S.pend[(P + 4) & 7] = __builtin_fmaf(S.wn4, y, S.pend[(P + 4) & 7]);
    S.pend[(P + 5) & 7] = __builtin_fmaf(S.wn5, y, S.pend[(P + 5) & 7]);

    // broadcast far acc of slot (P+7) (complete: last far tap d=7 added above)
    // and reset it on its owner lane for the next go-round
    constexpr int SB  = (P + 7) & 63;
    constexpr int KB  = SB >> 4;
    constexpr int OWB = SB & 15;
    float av;
    if constexpr (KB == 0) av = S.acc0;
    else if constexpr (KB == 1) av = S.acc1;
    else if constexpr (KB == 2) av = S.acc2;
    else av = S.acc3;
    S.bval = __int_as_float(
        __builtin_amdgcn_ds_swizzle(__float_as_int(av), (OWB << 5) | 0x10));
    float nv = (S.lane16 == OWB) ? 0.0f : av;
    if constexpr (KB == 0) S.acc0 = nv;
    else if constexpr (KB == 1) S.acc1 = nv;
    else if constexpr (KB == 2) S.acc2 = nv;
    else S.acc3 = nv;

    // batched coalesced store every 8 phases (lanes 0..7 of the group)
    if constexpr ((P & 7) == 7) {
        float a0 = S.m0 ? S.yv[1] : S.yv[0];
        float a1 = S.m0 ? S.yv[3] : S.yv[2];
        float a2 = S.m0 ? S.yv[5] : S.yv[4];
        float a3 = S.m0 ? S.yv[7] : S.yv[6];
        float b0 = S.m1 ? a1 : a0;
        float b1 = S.m1 ? a3 : a2;
        float sv = S.m2 ? b1 : b0;
        if (S.storer) S.yrow8[S.tbase + P - 7] = sv;
    }
}

template<int... Ps>
__device__ __forceinline__ void rec_steps(Rec& S, std::integer_sequence<int, Ps...>) {
    (rec_step<Ps>(S), ...);
}

__global__ __launch_bounds__(256) void k_rec(const float* __restrict__ u,
                                             const float* __restrict__ Wh,
                                             float* __restrict__ ybuf) {
    const int tid   = blockIdx.x * 256 + threadIdx.x;
    const int group = tid >> 4;          // 0..1599 == b*200 + c
    Rec S;
    S.lane16 = tid & 15;
    const int c = group % CHN;
    S.urow  = u    + (size_t)group * TP;
    S.yrow8 = ybuf + (size_t)group * TP + (S.lane16 & 7);
    S.m0 = (S.lane16 & 1) != 0;
    S.m1 = (S.lane16 & 2) != 0;
    S.m2 = (S.lane16 & 4) != 0;
    S.storer = S.lane16 < 8;
    const float* whc = Wh + c * TN;
    S.wn1 = whc[0]; S.wn2 = whc[1]; S.wn3 = whc[2];
    S.wn4 = whc[3]; S.wn5 = whc[4]; S.wn6 = whc[5];
    #pragma unroll
    for (int m = 0; m < 64; ++m) {
        int d = (S.lane16 + m) & 63;
        S.wl[m] = (d >= 7 && d <= TN) ? whc[d - 1] : 0.0f;
    }
    S.acc0 = S.acc1 = S.acc2 = S.acc3 = 0.f;
    #pragma unroll
    for (int i = 0; i < 8; ++i) S.pend[i] = 0.f;
    S.bval = 0.f;
    #pragma unroll
    for (int q = 0; q < 8; ++q) S.upipe[q] = *(const float4*)(&S.urow[4 * q]);

    for (int ob = 0; ob < NOB; ++ob) {
        S.tbase = ob * 64;
        rec_steps(S, std::make_integer_sequence<int, 64>{});
    }
}

// ---------------- phase D: out[b][t] = Vo + sum_c g[c]*y[b][c][t] ----------
// 4-way channel split, atomicAdd into zeroed out. 160 blocks.
__global__ __launch_bounds__(256) void k_out(const float* __restrict__ ybuf,
                                             const float* __restrict__ g,
                                             const float* __restrict__ Vo,
                                             float* __restrict__ out) {
    const int cchunk = blockIdx.x & 3;
    const int tb     = blockIdx.x >> 2;
    const int idx4   = tb * 256 + threadIdx.x;
    if (idx4 >= BN * TD / 4) return;
    const int t4 = idx4 * 4;
    const int b  = t4 / TD;            // 4-aligned, TD%4==0: no batch straddle
    const int tt = t4 - b * TD;
    const float* yp = ybuf + ((size_t)b * CHN + cchunk * 50) * TP + tt;
    const float* gp = g + cchunk * 50;
    float ax = 0.f, ay = 0.f, az = 0.f, aw = 0.f;
    if (cchunk == 0) { float v = Vo[0]; ax = ay = az = aw = v; }
    #pragma unroll 10
    for (int cc = 0; cc < 50; ++cc) {
        float4 y4 = *(const float4*)(yp + (size_t)cc * TP);
        float gc = gp[cc];
        ax = fmaf(gc, y4.x, ax);
        ay = fmaf(gc, y4.y, ay);
        az = fmaf(gc, y4.z, az);
        aw = fmaf(gc, y4.w, aw);
    }
    atomicAdd(out + t4 + 0, ax);
    atomicAdd(out + t4 + 1, ay);
    atomicAdd(out + t4 + 2, az);
    atomicAdd(out + t4 + 3, aw);
}

// ---------------------------------------------------------------------------
extern "C" void kernel_launch(void* const* d_in, const int* in_sizes, int n_in,
                              void* d_out, int out_size, void* d_ws, size_t ws_size,
                              hipStream_t stream) {
    const float* Se = (const float*)d_in[0];
    const float* Ce = (const float*)d_in[2];
    const float* Es = (const float*)d_in[4];
    const float* W1 = (const float*)d_in[6];
    const float* W2 = (const float*)d_in[7];
    const float* b1 = (const float*)d_in[8];
    const float* Wh = (const float*)d_in[9];
    const float* Vo = (const float*)d_in[11];
    float* ws  = (float*)d_ws;
    float* Cp  = ws + OFF_CP;
    float* g   = ws + OFF_G;
    float* syn = ws + OFF_SYN;
    float* u   = ws + OFF_U;
    float* yb  = ws + OFF_Y;
    float* out = (float*)d_out;

    hipMemsetAsync(d_out, 0, (size_t)out_size * sizeof(float), stream);
    hipLaunchKernelGGL(k_prep, dim3(158), dim3(256), 0, stream, Ce, Es, W2, Cp, g);
    hipLaunchKernelGGL(k_gemm, dim3(1250), dim3(256), 0, stream, Se, Cp, syn);
    hipLaunchKernelGGL(k_conv, dim3(BN * SUBN * HIDN), dim3(256), 0, stream, syn, W1, b1, u);
    hipLaunchKernelGGL(k_rec,  dim3(100), dim3(256), 0, stream, u, Wh, yb);
    hipLaunchKernelGGL(k_out,  dim3(160), dim3(256), 0, stream, yb, g, Vo, out);
}